// Round 1
// baseline (554.048 us; speedup 1.0000x reference)
//
#include <hip/hip_runtime.h>
#include <cstdint>
#include <cstddef>

#define B_  32
#define N_  512
#define T_  24
#define F_  64
#define FA_ 74

// d_ws float layout: [0,74) rowsum_W ; [128,704) W2[t_in*24+t_out] ; [768,1280) sigmoid(alpha)

__global__ __launch_bounds__(256) void params_kernel(
    const float* __restrict__ alpha, const float* __restrict__ w,
    const float* __restrict__ d, const float* __restrict__ w2,
    const float* __restrict__ d2, float* __restrict__ ws) {
  __shared__ float cs[FA_];
  int tid = threadIdx.x;
  if (tid < FA_) {
    float s = 0.f;
    for (int n = 0; n < FA_; ++n) s += w[n * FA_ + tid];
    cs[tid] = s;
  }
  __syncthreads();
  if (tid < FA_) {
    // rowsum_W[m] = sum_p w[m,p]*clip(d[p])*colsum_w[p]  (W symmetric => rowsum==colsum)
    float s = 0.f;
    for (int p = 0; p < FA_; ++p) {
      float dc = fminf(fmaxf(d[p], 0.f), 1.f);
      s += w[tid * FA_ + p] * dc * cs[p];
    }
    ws[tid] = s;
  }
  for (int e = tid; e < T_ * T_; e += 256) {
    int a = e / T_, b = e % T_;
    float s = 0.f;
    for (int p = 0; p < T_; ++p) {
      float dc = fminf(fmaxf(d2[p], 0.f), 1.f);
      s += w2[a * T_ + p] * dc * w2[b * T_ + p];
    }
    ws[128 + e] = s;
  }
  for (int i = tid; i < N_; i += 256) ws[768 + i] = 1.f / (1.f + __expf(-alpha[i]));
}

// pass1: out(b,i,t,f<64)   = 0.5*x + 0.25*S*rsW[f] + 0.25*xw2      (no relu yet; pass2 finishes)
//        out(b,i,t,m>=64)  = relu(0.25*S*rsW[m])                    (final)
// grid: 32 * 128 blocks (4 nodes per block), 256 threads
__global__ __launch_bounds__(256) void pass1_kernel(
    const float* __restrict__ x, const float* __restrict__ ws, float* __restrict__ out) {
  __shared__ float xs[4 * 24 * 65];  // [node][t*65 + f], pitch 65 kills t-stride bank conflicts
  __shared__ float Ss[4 * 24];
  int tid = threadIdx.x;
  int blk = blockIdx.x;
  int b = blk >> 7;
  int i0 = (blk & 127) << 2;
  const float* xb = x + (size_t)(b * N_ + i0) * (T_ * F_);

#pragma unroll
  for (int it = 0; it < 24; ++it) {
    int idx = it * 256 + tid;            // 0..6143 over 4 nodes * 1536
    int node = idx / 1536;
    int rem = idx - node * 1536;
    int t = rem >> 6, f = rem & 63;
    xs[node * 1560 + t * 65 + f] = xb[idx];
  }
  __syncthreads();
  if (tid < 96) {
    int node = tid / 24, t = tid - (tid / 24) * 24;
    float s = 0.f;
#pragma unroll
    for (int f = 0; f < 64; ++f) s += xs[node * 1560 + t * 65 + f];
    Ss[tid] = s;
  }
  __syncthreads();

  // main channels: thread -> (node, f)
  int node = tid >> 6, f = tid & 63;
  float xcol[24];
#pragma unroll
  for (int tp = 0; tp < 24; ++tp) xcol[tp] = xs[node * 1560 + tp * 65 + f];
  float accv[24];
#pragma unroll
  for (int t = 0; t < 24; ++t) accv[t] = 0.f;
  const float* __restrict__ W2p = ws + 128;  // uniform indices -> scalar loads
#pragma unroll
  for (int tp = 0; tp < 24; ++tp) {
    float xv = xcol[tp];
#pragma unroll
    for (int t = 0; t < 24; ++t) accv[t] += xv * W2p[tp * 24 + t];
  }
  float rsWf = ws[f];
  size_t base = (size_t)((b * N_ + i0 + node) * T_) * FA_ + f;
#pragma unroll
  for (int t = 0; t < 24; ++t) {
    float val = 0.5f * xcol[t] + 0.25f * Ss[node * 24 + t] * rsWf + 0.25f * accv[t];
    out[base + (size_t)t * FA_] = val;
  }

  // augmented channels m in [64,74): final value, relu here
  for (int e = tid; e < 4 * 24 * 10; e += 256) {
    int nd = e / 240;
    int rem = e - nd * 240;
    int t = rem / 10;
    int m = 64 + (rem - t * 10);
    float val = 0.25f * Ss[nd * 24 + t] * ws[m];
    out[(size_t)((b * N_ + i0 + nd) * T_ + t) * FA_ + m] = fmaxf(val, 0.f);
  }
}

// pass2: fp32 SIMT GEMM xa = adj @ x[b], fused finish: out = relu(E + 0.125*sig(alpha_i)*xa)
// grid dim3(12, 8, 32): col-tile (128 of 1536), node-tile (64 of 512), batch. 256 threads.
__global__ __launch_bounds__(256) void pass2_kernel(
    const float* __restrict__ x, const float* __restrict__ adj,
    const float* __restrict__ ws, float* __restrict__ out) {
  const int b = blockIdx.z;
  const int i0 = blockIdx.y * 64;
  const int c0 = blockIdx.x * 128;
  __shared__ float adjs[16 * 68];   // [k][i], pitch 68
  __shared__ float xsh[16 * 128];   // [k][c]
  float acc[8][4];
#pragma unroll
  for (int r = 0; r < 8; ++r)
#pragma unroll
    for (int cc = 0; cc < 4; ++cc) acc[r][cc] = 0.f;

  int tid = threadIdx.x;
  int tx = tid & 31;   // cols c0 + tx*4 .. +3
  int ty = tid >> 5;   // rows i0 + ty*8 .. +7
  const float* xb = x + (size_t)b * N_ * (T_ * F_);

  for (int k0 = 0; k0 < 512; k0 += 16) {
#pragma unroll
    for (int it = 0; it < 4; ++it) {
      int idx = it * 256 + tid;        // 1024 = 64 rows * 16 k
      int i = idx >> 4, k = idx & 15;
      adjs[k * 68 + i] = adj[(size_t)(i0 + i) * 512 + k0 + k];
    }
#pragma unroll
    for (int it = 0; it < 2; ++it) {
      int idx = it * 256 + tid;        // 512 float4 = 16 k * 32 c4
      int c4 = idx & 31, k = idx >> 5;
      float4 v = *(const float4*)&xb[(size_t)(k0 + k) * 1536 + c0 + c4 * 4];
      *(float4*)&xsh[k * 128 + c4 * 4] = v;
    }
    __syncthreads();
#pragma unroll
    for (int kk = 0; kk < 16; ++kk) {
      float bb[4];
      *(float4*)bb = *(const float4*)&xsh[kk * 128 + tx * 4];
      float aa[8];
      *(float4*)&aa[0] = *(const float4*)&adjs[kk * 68 + ty * 8];
      *(float4*)&aa[4] = *(const float4*)&adjs[kk * 68 + ty * 8 + 4];
#pragma unroll
      for (int r = 0; r < 8; ++r)
#pragma unroll
        for (int cc = 0; cc < 4; ++cc) acc[r][cc] += aa[r] * bb[cc];
    }
    __syncthreads();
  }

#pragma unroll
  for (int r = 0; r < 8; ++r) {
    int i = i0 + ty * 8 + r;
    float coeff = 0.125f * ws[768 + i];
#pragma unroll
    for (int cc = 0; cc < 4; ++cc) {
      int c = c0 + tx * 4 + cc;
      int t = c >> 6, f = c & 63;
      size_t o = (size_t)((b * N_ + i) * T_ + t) * FA_ + f;
      float val = out[o] + coeff * acc[r][cc];
      out[o] = fmaxf(val, 0.f);
    }
  }
}

extern "C" void kernel_launch(void* const* d_in, const int* in_sizes, int n_in,
                              void* d_out, int out_size, void* d_ws, size_t ws_size,
                              hipStream_t stream) {
  const float* x     = (const float*)d_in[0];
  const float* adj   = (const float*)d_in[1];
  const float* alpha = (const float*)d_in[2];
  const float* w     = (const float*)d_in[3];
  const float* d     = (const float*)d_in[4];
  const float* w2    = (const float*)d_in[5];
  const float* d2    = (const float*)d_in[6];
  float* out = (float*)d_out;
  float* ws  = (float*)d_ws;

  hipLaunchKernelGGL(params_kernel, dim3(1), dim3(256), 0, stream,
                     alpha, w, d, w2, d2, ws);
  hipLaunchKernelGGL(pass1_kernel, dim3(B_ * (N_ / 4)), dim3(256), 0, stream,
                     x, ws, out);
  hipLaunchKernelGGL(pass2_kernel, dim3(12, 8, B_), dim3(256), 0, stream,
                     x, adj, ws, out);
}

// Round 2
// 345.501 us; speedup vs baseline: 1.6036x; 1.6036x over previous
//
#include <hip/hip_runtime.h>
#include <hip/hip_bf16.h>
#include <cstdint>
#include <cstddef>

#define B_  32
#define N_  512
#define T_  24
#define F_  64
#define FA_ 74
#define NC  1536   // T_*F_ columns per node-row

typedef __attribute__((ext_vector_type(8))) short short8;
typedef __attribute__((ext_vector_type(4))) float floatx4;

// ws float layout:
//  [0,74)              rsW (rowsum of W)
//  [128,704)           W2 (symmetric, row-major 24x24)
//  [768,1280)          sigmoid(alpha) [512]
//  [1536,132608)       adjB  bf16[512*512], natural [i][k]
//  [132608,+12582912)  xT    bf16[b][c][k]  (32*1536*512)   ~48 MB
#define WS_ADJB 1536
#define WS_XT   132608

#define AS1(p) ((const __attribute__((address_space(1))) void*)(p))
#define AS3(p) ((__attribute__((address_space(3))) void*)(p))

__global__ __launch_bounds__(256) void params_kernel(
    const float* __restrict__ alpha, const float* __restrict__ w,
    const float* __restrict__ d, const float* __restrict__ w2,
    const float* __restrict__ d2, float* __restrict__ ws) {
  __shared__ float cs[FA_];
  int tid = threadIdx.x;
  if (tid < FA_) {
    float s = 0.f;
    for (int n = 0; n < FA_; ++n) s += w[n * FA_ + tid];
    cs[tid] = s;
  }
  __syncthreads();
  if (tid < FA_) {
    float s = 0.f;
    for (int p = 0; p < FA_; ++p) {
      float dc = fminf(fmaxf(d[p], 0.f), 1.f);
      s += w[tid * FA_ + p] * dc * cs[p];
    }
    ws[tid] = s;
  }
  for (int e = tid; e < T_ * T_; e += 256) {
    int a = e / T_, b = e % T_;
    float s = 0.f;
    for (int p = 0; p < T_; ++p) {
      float dc = fminf(fmaxf(d2[p], 0.f), 1.f);
      s += w2[a * T_ + p] * dc * w2[b * T_ + p];
    }
    ws[128 + e] = s;
  }
  for (int i = tid; i < N_; i += 256) ws[768 + i] = 1.f / (1.f + __expf(-alpha[i]));
}

// adj fp32 -> bf16, natural layout. grid 256 blocks x 256 thr, 4 elems/thread.
__global__ __launch_bounds__(256) void convert_adj_kernel(
    const float* __restrict__ adj, float* __restrict__ ws) {
  __hip_bfloat16* adjB = (__hip_bfloat16*)(ws + WS_ADJB);
  int g = (blockIdx.x * 256 + threadIdx.x) * 4;
  float4 v = *(const float4*)&adj[g];
  ushort4 u;
  __hip_bfloat16 h;
  h = __float2bfloat16(v.x); u.x = *(unsigned short*)&h;
  h = __float2bfloat16(v.y); u.y = *(unsigned short*)&h;
  h = __float2bfloat16(v.z); u.z = *(unsigned short*)&h;
  h = __float2bfloat16(v.w); u.w = *(unsigned short*)&h;
  *(ushort4*)&adjB[g] = u;
}

// x[b][k][c] fp32  ->  xT[b][c][k] bf16.  64x64 tiles. grid (24, 8, 32).
__global__ __launch_bounds__(256) void transpose_x_kernel(
    const float* __restrict__ x, float* __restrict__ ws) {
  __hip_bfloat16* xT = (__hip_bfloat16*)(ws + WS_XT);
  __shared__ float tile[64 * 65];
  int tid = threadIdx.x;
  int b = blockIdx.z;
  int c0 = blockIdx.x * 64;
  int k0 = blockIdx.y * 64;
#pragma unroll
  for (int it = 0; it < 4; ++it) {
    int g = it * 256 + tid;      // 1024 float4 = 64 k x 16 c4
    int k = g >> 4, c4 = g & 15;
    float4 v = *(const float4*)&x[((size_t)(b * N_ + k0 + k)) * NC + c0 + c4 * 4];
    tile[k * 65 + c4 * 4 + 0] = v.x;
    tile[k * 65 + c4 * 4 + 1] = v.y;
    tile[k * 65 + c4 * 4 + 2] = v.z;
    tile[k * 65 + c4 * 4 + 3] = v.w;
  }
  __syncthreads();
#pragma unroll
  for (int it = 0; it < 4; ++it) {
    int h = it * 256 + tid;      // 1024 = 64 c x 16 k4
    int c = h >> 4, k4 = h & 15;
    ushort4 u;
    __hip_bfloat16 hb;
    hb = __float2bfloat16(tile[(k4 * 4 + 0) * 65 + c]); u.x = *(unsigned short*)&hb;
    hb = __float2bfloat16(tile[(k4 * 4 + 1) * 65 + c]); u.y = *(unsigned short*)&hb;
    hb = __float2bfloat16(tile[(k4 * 4 + 2) * 65 + c]); u.z = *(unsigned short*)&hb;
    hb = __float2bfloat16(tile[(k4 * 4 + 3) * 65 + c]); u.w = *(unsigned short*)&hb;
    *(ushort4*)&xT[((size_t)b * NC + c0 + c) * 512 + k0 + k4 * 4] = u;
  }
}

// pass1: E = 0.5x + 0.25*S*rsW[f] + 0.25*(W2 t-mix)  for f<64 (no relu yet);
//        aug channels m>=64: relu(0.25*S*rsW[m]) final.
// grid 32*128 (4 nodes/block), 256 thr, thread <-> (node, f).
__global__ __launch_bounds__(256) void pass1_kernel(
    const float* __restrict__ x, const float* __restrict__ ws, float* __restrict__ out) {
  __shared__ float xs[4 * T_ * FA_];   // 7104 floats: staged x (pitch 64) then E (pitch 74)
  __shared__ float Ss[4 * T_];
  __shared__ float rsWs[80];
  int tid = threadIdx.x;
  int blk = blockIdx.x;
  int b = blk >> 7;
  int i0 = (blk & 127) << 2;
  const float* xb = x + (size_t)(b * N_ + i0) * NC;

  if (tid < FA_) rsWs[tid] = ws[tid];
  // stage: LDS layout == global layout, zero index math
#pragma unroll
  for (int it = 0; it < 6; ++it) {
    int g = it * 256 + tid;            // 1536 float4
    *(float4*)&xs[g * 4] = *(const float4*)&xb[g * 4];
  }
  __syncthreads();

  int node = tid >> 6, f = tid & 63;
  float xcol[24];
#pragma unroll
  for (int t = 0; t < 24; ++t) xcol[t] = xs[node * 1536 + t * 64 + f];
  __syncthreads();   // all xs reads done; xs reusable for E

  // S[t] = wave-wide sum over f (lanes 0..63 of this wave are exactly f 0..63)
  float S[24];
#pragma unroll
  for (int t = 0; t < 24; ++t) S[t] = xcol[t];
#pragma unroll
  for (int off = 32; off >= 1; off >>= 1) {
#pragma unroll
    for (int t = 0; t < 24; ++t) S[t] += __shfl_xor(S[t], off, 64);
  }
  if ((tid & 63) == 0) {
#pragma unroll
    for (int t = 0; t < 24; ++t) Ss[node * 24 + t] = S[t];
  }

  // t-mix: accv[to] = sum_tp xcol[tp] * W2[to][tp]   (W2 symmetric; uniform loads)
  const float* __restrict__ W2p = ws + 128;
  float accv[24];
#pragma unroll
  for (int to = 0; to < 24; ++to) {
    float a = 0.f;
#pragma unroll
    for (int tp = 0; tp < 24; ++tp) a += xcol[tp] * W2p[to * 24 + tp];
    accv[to] = a;
  }
  float rsWf = rsWs[f];
#pragma unroll
  for (int t = 0; t < 24; ++t) {
    float val = 0.5f * xcol[t] + 0.25f * S[t] * rsWf + 0.25f * accv[t];
    xs[node * 1776 + t * 74 + f] = val;
  }
  __syncthreads();

  // aug channels: 4 nodes * 24 t * 10 m = 960
#pragma unroll
  for (int it = 0; it < 4; ++it) {
    int e = it * 256 + tid;
    if (e < 960) {
      int nd = e / 240;
      int rem = e - nd * 240;
      int t = rem / 10;
      int m = rem - t * 10;
      float val = 0.25f * Ss[nd * 24 + t] * rsWs[64 + m];
      xs[nd * 1776 + t * 74 + 64 + m] = fmaxf(val, 0.f);
    }
  }
  __syncthreads();

  // stream out: 7104 floats = 1776 float4, fully coalesced
  float* outb = out + (size_t)(b * N_ + i0) * 1776;
#pragma unroll
  for (int it = 0; it < 7; ++it) {
    int g = it * 256 + tid;
    if (g < 1776) *(float4*)&outb[g * 4] = *(float4*)&xs[g * 4];
  }
}

// MFMA GEMM: xa = adj @ x[b]; epilogue out = relu(E + 0.125*sig(alpha_i)*xa)
// 128x128 tile, K=512, BK=32, 16x16x32 bf16 MFMA, m97 structure.
// grid (12, 4, 32), 256 thr (4 waves, each 64x64 quadrant as 4x4 MFMA tiles).
__global__ __launch_bounds__(256) void gemm_kernel(
    const float* __restrict__ ws, float* __restrict__ out) {
  const unsigned short* adjB = (const unsigned short*)(ws + WS_ADJB);
  const unsigned short* xT   = (const unsigned short*)(ws + WS_XT);
  __shared__ short As[128 * 32];
  __shared__ short Bs[128 * 32];

  int tid = threadIdx.x;
  int b  = blockIdx.z;
  int i0 = blockIdx.y * 128;
  int c0 = blockIdx.x * 128;
  int wave = tid >> 6, lane = tid & 63;
  int mw = (wave & 1) * 64, nw = (wave >> 1) * 64;
  int l15 = lane & 15, l4 = lane >> 4;

  floatx4 acc[4][4];
#pragma unroll
  for (int mt = 0; mt < 4; ++mt)
#pragma unroll
    for (int nt = 0; nt < 4; ++nt) acc[mt][nt] = (floatx4){0.f, 0.f, 0.f, 0.f};

  const size_t bRow = (size_t)b * NC;
  for (int k0 = 0; k0 < 512; k0 += 32) {
#pragma unroll
    for (int rep = 0; rep < 2; ++rep) {
      int chunk = rep * 256 + tid;       // 512 chunks of 8 bf16
      int r = chunk >> 2;                // row (i for A, c for B)
      int k8 = (chunk & 3) * 8;
      __builtin_amdgcn_global_load_lds(AS1(adjB + (size_t)(i0 + r) * 512 + k0 + k8),
                                       AS3(&As[chunk * 8]), 16, 0, 0);
      __builtin_amdgcn_global_load_lds(AS1(xT + (bRow + c0 + r) * 512 + k0 + k8),
                                       AS3(&Bs[chunk * 8]), 16, 0, 0);
    }
    __syncthreads();

    short8 af[4], bf[4];
#pragma unroll
    for (int mt = 0; mt < 4; ++mt)
      af[mt] = *(const short8*)&As[(mw + mt * 16 + l15) * 32 + l4 * 8];
#pragma unroll
    for (int nt = 0; nt < 4; ++nt)
      bf[nt] = *(const short8*)&Bs[(nw + nt * 16 + l15) * 32 + l4 * 8];
#pragma unroll
    for (int mt = 0; mt < 4; ++mt)
#pragma unroll
      for (int nt = 0; nt < 4; ++nt)
        acc[mt][nt] = __builtin_amdgcn_mfma_f32_16x16x32_bf16(af[mt], bf[nt], acc[mt][nt], 0, 0, 0);
    __syncthreads();
  }

  // epilogue: C/D layout col=lane&15, row=(lane>>4)*4+reg
  float coeff[4][4];
#pragma unroll
  for (int mt = 0; mt < 4; ++mt)
#pragma unroll
    for (int r = 0; r < 4; ++r)
      coeff[mt][r] = 0.125f * ws[768 + i0 + mw + mt * 16 + l4 * 4 + r];

#pragma unroll
  for (int mt = 0; mt < 4; ++mt) {
#pragma unroll
    for (int nt = 0; nt < 4; ++nt) {
      int col = c0 + nw + nt * 16 + l15;
      int t = col >> 6, f = col & 63;
#pragma unroll
      for (int r = 0; r < 4; ++r) {
        int row = i0 + mw + mt * 16 + l4 * 4 + r;
        size_t o = ((size_t)(b * N_ + row) * T_ + t) * FA_ + f;
        float val = out[o] + coeff[mt][r] * acc[mt][nt][r];
        out[o] = fmaxf(val, 0.f);
      }
    }
  }
}

extern "C" void kernel_launch(void* const* d_in, const int* in_sizes, int n_in,
                              void* d_out, int out_size, void* d_ws, size_t ws_size,
                              hipStream_t stream) {
  const float* x     = (const float*)d_in[0];
  const float* adj   = (const float*)d_in[1];
  const float* alpha = (const float*)d_in[2];
  const float* w     = (const float*)d_in[3];
  const float* d     = (const float*)d_in[4];
  const float* w2    = (const float*)d_in[5];
  const float* d2    = (const float*)d_in[6];
  float* out = (float*)d_out;
  float* ws  = (float*)d_ws;

  hipLaunchKernelGGL(params_kernel, dim3(1), dim3(256), 0, stream,
                     alpha, w, d, w2, d2, ws);
  hipLaunchKernelGGL(convert_adj_kernel, dim3(256), dim3(256), 0, stream, adj, ws);
  hipLaunchKernelGGL(transpose_x_kernel, dim3(24, 8, B_), dim3(256), 0, stream, x, ws);
  hipLaunchKernelGGL(pass1_kernel, dim3(B_ * (N_ / 4)), dim3(256), 0, stream, x, ws, out);
  hipLaunchKernelGGL(gemm_kernel, dim3(12, 4, B_), dim3(256), 0, stream, ws, out);
}